// Round 16
// baseline (199.666 us; speedup 1.0000x reference)
//
#include <hip/hip_runtime.h>
#include <hip/hip_fp16.h>

// SoftFreezeAttention on MI355X (gfx950).
// out = softmax_rows(exp(-cdist(X,P)/efft)) @ V  with NO max-subtraction
// (reference underflows to 0; computed honestly).
//
// All-fp8 two-pass pipeline (chunks=1):
//   prep_all: X->X8+x2, P->P8+p2, V->Vt8, invt  (1 launch)
//   passA: fp8 GEMM X8.P8^T -> W8 = exp(-dist*invt), N-loop x4, epilogue
//          via XOR-swizzled f16 LDS tile in buf1 + nt stores + rowsum.
//   rowsum_k; passB: fp8 GEMM O^T = Vt8 . W8^T, transpose + normalize.
//
// History: R11 all-fp8 159.3 -> R14 prep-fusion + N-loop = 154.4 (BEST;
// passA 94, VGPR 116, occ 20%) -> R15 T14 + FULL-UNROLL REGRESSED (189.7):
// VGPR 116->156 crossed the 128 step, occupancy halved to 1 blk/CU.
// R16 = R14 base + ONLY the T14 epilogue-prefetch (runtime Kb, unroll 2,
// no template): prefetch j+1's tile0 into buf0 after the final K-barrier;
// epilogue (~1400cy, Wt in buf1, row-XOR swizzle <=2-way=free) covers the
// ~900cy latency; j-top barrier then finds loads complete.

typedef _Float16 f16;
typedef _Float16 f16x8 __attribute__((ext_vector_type(8)));
typedef float f32x4 __attribute__((ext_vector_type(4)));
typedef int i32x4 __attribute__((ext_vector_type(4)));
typedef unsigned char u8;

#define DEV __device__ __forceinline__

DEV void gload16(const void* g, void* l) {
  __builtin_amdgcn_global_load_lds(
      (const __attribute__((address_space(1))) void*)g,
      (__attribute__((address_space(3))) void*)l, 16, 0, 0);
}

// pack 4 f32 -> 4 fp8 e4m3 bytes (OCP), little-endian [a,b,c,d]
DEV int pack4_fp8(float a, float b, float c, float d) {
  int lo = __builtin_amdgcn_cvt_pk_fp8_f32(a, b, 0, false);
  int hi = __builtin_amdgcn_cvt_pk_fp8_f32(c, d, 0, false);
  return (hi << 16) | (lo & 0xffff);
}

// ---------------------------------------------------------------- fused prep

DEV void row_pack(const float* __restrict__ src, u8* __restrict__ dst,
                  float* __restrict__ sq, int blk) {
  int row  = blk * 4 + (threadIdx.x >> 6);
  int lane = threadIdx.x & 63;
  const float* r = src + (size_t)row * 512 + lane * 8;
  float4 a = *(const float4*)r;
  float4 b = *(const float4*)(r + 4);
  int2 pk;
  pk.x = pack4_fp8(a.x, a.y, a.z, a.w);
  pk.y = pack4_fp8(b.x, b.y, b.z, b.w);
  *(int2*)(dst + (size_t)row * 512 + lane * 8) = pk;
  float ss = a.x*a.x + a.y*a.y + a.z*a.z + a.w*a.w
           + b.x*b.x + b.y*b.y + b.z*b.z + b.w*b.w;
  ss += __shfl_xor(ss, 1);  ss += __shfl_xor(ss, 2);  ss += __shfl_xor(ss, 4);
  ss += __shfl_xor(ss, 8);  ss += __shfl_xor(ss, 16); ss += __shfl_xor(ss, 32);
  if (lane == 0) sq[row] = ss;
}

__global__ __launch_bounds__(256) void prep_all(
    const float* __restrict__ x, const float* __restrict__ pos,
    const float* __restrict__ val, const float* __restrict__ T,
    const float* __restrict__ ns,
    u8* __restrict__ X8, u8* __restrict__ P8, u8* __restrict__ Vt8,
    float* __restrict__ x2, float* __restrict__ p2,
    float* __restrict__ invt) {
  __shared__ f16 Tt[64][72];
  int b = blockIdx.x;
  if (b < 4096) {                      // X: 16384 rows
    row_pack(x, X8, x2, b);
  } else if (b < 5120) {               // P: 4096 rows
    row_pack(pos, P8, p2, b - 4096);
  } else if (b < 5632) {               // Vt: 512 64x64 tiles
    int id = b - 5120;
    int n0 = (id & 63) * 64, d0 = (id >> 6) * 64;
    int t = threadIdx.x;
#pragma unroll
    for (int rr = 0; rr < 4; ++rr) {
      int r  = (t >> 4) + rr * 16;
      int cq = t & 15;
      float4 v = *(const float4*)(val + (size_t)(n0 + r) * 512 + d0 + cq * 4);
      Tt[cq*4+0][r] = (f16)v.x; Tt[cq*4+1][r] = (f16)v.y;
      Tt[cq*4+2][r] = (f16)v.z; Tt[cq*4+3][r] = (f16)v.w;
    }
    __syncthreads();
    int rd = t >> 2, part = t & 3;
    f16x8 o0 = *(const f16x8*)&Tt[rd][part * 16];
    f16x8 o1 = *(const f16x8*)&Tt[rd][part * 16 + 8];
    i32x4 pk;
    pk.x = pack4_fp8((float)o0[0], (float)o0[1], (float)o0[2], (float)o0[3]);
    pk.y = pack4_fp8((float)o0[4], (float)o0[5], (float)o0[6], (float)o0[7]);
    pk.z = pack4_fp8((float)o1[0], (float)o1[1], (float)o1[2], (float)o1[3]);
    pk.w = pack4_fp8((float)o1[4], (float)o1[5], (float)o1[6], (float)o1[7]);
    *(i32x4*)(Vt8 + (size_t)(d0 + rd) * 4096 + n0 + part * 16) = pk;
  } else {                             // invt: 16 blocks x 256
    int i = (b - 5632) * 256 + threadIdx.x;
    invt[i] = 1.0f / ((fabsf(T[i]) + 0.1f) * ns[i]);
  }
}

// ------------------------------------------------- main GEMM (C = A . B^T form)
// All-fp8. 128x128 tile, 4 waves 2x2, 4x4 16x16x32 frags/wave.
// K-tile = 128 B. LDS dbuf [buf0|buf1] = 64KB. Tiles [128 r][128 B];
// 16B-chunk o of row r stored at o^(r&7); global_load_lds pre-swizzled src.
// 2-phase: stage(next) BEFORE compute(cur), one barrier/iter (unroll 2,
// runtime Kb — R15's full unroll cost 40 VGPR and halved occupancy).
// EPI 0: N-loop nrep=4; T14: j+1's tile0 prefetched into buf0 before j's
//        epilogue (Wt lives entirely in buf1, row-XOR chunk swizzle).
template <int EPI>
__global__ __launch_bounds__(256) void gemm_bt(
    const void* __restrict__ A, const void* __restrict__ B, int Kb, int gx,
    const float* __restrict__ x2, const float* __restrict__ p2,
    const float* __restrict__ invt, u8* __restrict__ Wout,
    float* __restrict__ Wpart,
    const float* __restrict__ rowsum, float* __restrict__ outp) {
  __shared__ __align__(16) char smem[65536];
  char* As = smem;            // +cur: 0 or 32768
  char* Bs = smem + 16384;

  const int nwg = gridDim.x;
  const int sid = (blockIdx.x & 7) * (nwg >> 3) + (blockIdx.x >> 3);
  const int bx = sid % gx, by = sid / gx;

  const int tid = threadIdx.x, lane = tid & 63, w = tid >> 6;
  const int wrow = (w >> 1) * 64, wcol = (w & 1) * 64;
  const int g = lane >> 4, r15 = lane & 15;
  const int m0 = by * 128;

  const char* Ablk = (const char*)A + (size_t)m0 * Kb;

  const int lr = lane >> 3;
  const int lo = (lane & 7) ^ lr;
  const char* aSrc[4]; char* aDst[4]; char* bDst[4];
  int srow[4];
#pragma unroll
  for (int i = 0; i < 4; ++i) {
    int cb  = w * 4 + i;
    srow[i] = cb * 8 + lr;
    aSrc[i] = Ablk + (size_t)srow[i] * Kb + 16 * lo;
    aDst[i] = As + cb * 1024;
    bDst[i] = Bs + cb * 1024;
  }

  int abase[4], asw[4], bbase[4], bsw[4];
#pragma unroll
  for (int mt = 0; mt < 4; ++mt) {
    int r = wrow + mt * 16 + r15;
    abase[mt] = r * 128; asw[mt] = (r & 7) << 4;
    int rb = wcol + mt * 16 + r15;
    bbase[mt] = rb * 128; bsw[mt] = (rb & 7) << 4;
  }

  const int NIT  = Kb >> 7;
  constexpr int nrep = (EPI == 0) ? 4 : 1;

  // prologue: stage tile0 of j=0 into buf0
  {
    const char* Bblk0 = (const char*)B + (size_t)(bx * nrep * 128) * Kb;
#pragma unroll
    for (int i = 0; i < 4; ++i) gload16(aSrc[i], aDst[i]);
#pragma unroll
    for (int i = 0; i < 4; ++i)
      gload16(Bblk0 + (size_t)srow[i] * Kb + 16 * lo, bDst[i]);
  }

  for (int j = 0; j < nrep; ++j) {
    const int bxj = bx * nrep + j;
    const int n0 = bxj * 128;
    const char* Bblk = (const char*)B + (size_t)n0 * Kb;
    const char* bSrc[4];
#pragma unroll
    for (int i = 0; i < 4; ++i)
      bSrc[i] = Bblk + (size_t)srow[i] * Kb + 16 * lo;

    // drains tile0 gloads (prologue or previous epilogue's T14 prefetch);
    // retires previous epilogue's Wt reads before it=0 stages into buf1.
    __syncthreads();
    f32x4 acc[4][4] = {};

#pragma unroll 2
    for (int it = 0; it < NIT; ++it) {
      const int cur = (it & 1) << 15;
      const int nxt = cur ^ 32768;
      if (it + 1 < NIT) {                  // issue next-tile loads FIRST
        const int kb1 = (it + 1) << 7;
#pragma unroll
        for (int i = 0; i < 4; ++i) gload16(aSrc[i] + kb1, aDst[i] + nxt);
#pragma unroll
        for (int i = 0; i < 4; ++i) gload16(bSrc[i] + kb1, bDst[i] + nxt);
      }
      const char* As_ = As + cur;
      const char* Bs_ = Bs + cur;
#pragma unroll
      for (int ks = 0; ks < 4; ++ks) {     // 4 k-slices of K=32 fp8
        long aL[4], bL[4];
#pragma unroll
        for (int mt = 0; mt < 4; ++mt)
          aL[mt] = *(const long*)(As_ + (abase[mt] + ((32 * ks + 8 * g) ^ asw[mt])));
#pragma unroll
        for (int nt = 0; nt < 4; ++nt)
          bL[nt] = *(const long*)(Bs_ + (bbase[nt] + ((32 * ks + 8 * g) ^ bsw[nt])));
#pragma unroll
        for (int mt = 0; mt < 4; ++mt)
#pragma unroll
          for (int nt = 0; nt < 4; ++nt)
            acc[mt][nt] = __builtin_amdgcn_mfma_f32_16x16x32_fp8_fp8(aL[mt], bL[nt],
                                                                     acc[mt][nt], 0, 0, 0);
      }
      __syncthreads();
    }
    // after final barrier both buffers' reads are retired.

    if constexpr (EPI == 0) {
      // T14 prefetch: issue j+1's tile0 into buf0 NOW; the epilogue below
      // covers its latency. Wt lives entirely in buf1 so no overlap.
      if (j + 1 < nrep) {
        const char* Bn = (const char*)B + (size_t)((bxj + 1) * 128) * Kb;
#pragma unroll
        for (int i = 0; i < 4; ++i) gload16(aSrc[i], aDst[i]);
#pragma unroll
        for (int i = 0; i < 4; ++i)
          gload16(Bn + (size_t)srow[i] * Kb + 16 * lo, bDst[i]);
      }
      // ---- epilogue: wv = exp(-dist*invt) -> Wt (buf1, [128 rows][256B]
      // f16, row-XOR chunk swizzle: byte = ml*256 + ((2*nl) ^ ((ml&7)<<4)))
      // -> coalesced readback: sum + fp8 pack + 4x i32x4 nt-stores.
      char* Wt = smem + 32768;
      int nloc[4]; float p2v[4], itv[4];
#pragma unroll
      for (int nt = 0; nt < 4; ++nt) {
        int nl = wcol + nt * 16 + r15;
        nloc[nt] = nl; p2v[nt] = p2[n0 + nl]; itv[nt] = invt[n0 + nl];
      }
#pragma unroll
      for (int mt = 0; mt < 4; ++mt) {
#pragma unroll
        for (int reg = 0; reg < 4; ++reg) {
          int ml = wrow + mt * 16 + g * 4 + reg;
          int mlsw = (ml & 7) << 4;
          float xx = x2[m0 + ml];
#pragma unroll
          for (int nt = 0; nt < 4; ++nt) {
            float d2 = xx + p2v[nt] - 2.0f * acc[mt][nt][reg];
            float dist = __builtin_amdgcn_sqrtf(fmaxf(d2, 0.0f));
            float wv = __expf(-dist * itv[nt]);
            *(f16*)(Wt + ml * 256 + ((2 * nloc[nt]) ^ mlsw)) = (f16)wv;
          }
        }
      }
      __syncthreads();
      {
        int r = tid >> 1, half = tid & 1;
        int r7 = r & 7;
        float s = 0.f;
        int wds[16];
#pragma unroll
        for (int i = 0; i < 8; ++i) {
          int c = half * 8 + i;                 // logical 16B chunk
          f16x8 v = *(const f16x8*)(Wt + r * 256 + ((c ^ r7) << 4));
          float f0=(float)v[0], f1=(float)v[1], f2=(float)v[2], f3=(float)v[3];
          float f4=(float)v[4], f5=(float)v[5], f6=(float)v[6], f7=(float)v[7];
          s += f0+f1+f2+f3+f4+f5+f6+f7;
          wds[i*2]   = pack4_fp8(f0, f1, f2, f3);
          wds[i*2+1] = pack4_fp8(f4, f5, f6, f7);
        }
        u8* dstp = Wout + (size_t)(m0 + r) * 4096 + n0 + half * 64;
#pragma unroll
        for (int q = 0; q < 4; ++q) {
          i32x4 st = { wds[q*4], wds[q*4+1], wds[q*4+2], wds[q*4+3] };
          __builtin_nontemporal_store(st, (i32x4*)(dstp + q * 16));
        }
        Wpart[(size_t)(m0 + r) * 64 + bxj * 2 + half] = s;
      }
    } else {
      // ---- pass B epilogue: O^T transpose via per-wave LDS + normalize
      float* Tb = (float*)(smem) + w * (32 * 66);
      const int dl = lane & 31, half = lane >> 5;
#pragma unroll
      for (int h = 0; h < 2; ++h) {
#pragma unroll
        for (int mh = 0; mh < 2; ++mh) {
          int mt = h * 2 + mh;
#pragma unroll
          for (int nt = 0; nt < 4; ++nt)
#pragma unroll
            for (int reg = 0; reg < 4; ++reg)
              Tb[(mh * 16 + g * 4 + reg) * 66 + nt * 16 + r15] = acc[mt][nt][reg];
        }
#pragma unroll
        for (int rr = 0; rr < 32; ++rr) {
          int mloc = rr * 2 + half;
          float v = Tb[dl * 66 + mloc];
          int mg = n0 + wcol + mloc;
          int dg = m0 + wrow + h * 32 + dl;
          float nrm = 1.0f / (rowsum[mg] + 1e-8f);
          __builtin_nontemporal_store(v * nrm, &outp[(size_t)mg * 512 + dg]);
        }
        __syncthreads();  // Tb reused next h
      }
    }
  }
}

// rowsum[m] = sum of 64 partials
__global__ __launch_bounds__(256) void rowsum_k(const float* __restrict__ Wpart,
                                                float* __restrict__ rowsum) {
  int row  = blockIdx.x * 4 + (threadIdx.x >> 6);
  int lane = threadIdx.x & 63;
  float v = Wpart[(size_t)row * 64 + lane];
  v += __shfl_xor(v, 1);  v += __shfl_xor(v, 2);  v += __shfl_xor(v, 4);
  v += __shfl_xor(v, 8);  v += __shfl_xor(v, 16); v += __shfl_xor(v, 32);
  if (lane == 0) rowsum[row] = v;
}

// ---------------------------------------------------------------------- launch

extern "C" void kernel_launch(void* const* d_in, const int* in_sizes, int n_in,
                              void* d_out, int out_size, void* d_ws, size_t ws_size,
                              hipStream_t stream) {
  const float* x   = (const float*)d_in[0];
  const float* pos = (const float*)d_in[1];
  const float* val = (const float*)d_in[2];
  const float* tmp = (const float*)d_in[3];
  const float* nsc = (const float*)d_in[4];
  float* out = (float*)d_out;

  char* p = (char*)d_ws;
  u8*    X8     = (u8*)p;    p += (size_t)16384 * 512;
  u8*    P8     = (u8*)p;    p += (size_t)4096 * 512;
  u8*    Vt8    = (u8*)p;    p += (size_t)512 * 4096;
  float* x2     = (float*)p; p += (size_t)16384 * 4;
  float* p2     = (float*)p; p += (size_t)4096 * 4;
  float* invt   = (float*)p; p += (size_t)4096 * 4;
  float* rowsum = (float*)p; p += (size_t)16384 * 4;
  float* Wpart  = (float*)p; p += (size_t)16384 * 64 * 4;
  u8*    W8     = (u8*)p;
  size_t fixed  = (size_t)(p - (char*)d_ws);
  size_t wfull  = (size_t)16384 * 4096;   // fp8 W

  if (fixed + wfull > ws_size) return;

  prep_all<<<5648, 256, 0, stream>>>(x, pos, val, tmp, nsc,
                                     X8, P8, Vt8, x2, p2, invt);

  // pass A: Kb = 512 fp8 bytes/row, NIT = 4, N-loop x4 -> grid 8 * 128
  gemm_bt<0><<<8 * 128, 256, 0, stream>>>(
      X8, P8, 512, 8, x2, p2, invt, W8, Wpart, nullptr, nullptr);
  rowsum_k<<<4096, 256, 0, stream>>>(Wpart, rowsum);
  // pass B: Kb = 4096 fp8 bytes/row, NIT = 32
  gemm_bt<1><<<128 * 4, 256, 0, stream>>>(
      Vt8, W8, 4096, 128, nullptr, nullptr, nullptr, nullptr, nullptr,
      rowsum, out);
}

// Round 17
// 154.083 us; speedup vs baseline: 1.2958x; 1.2958x over previous
//
#include <hip/hip_runtime.h>
#include <hip/hip_fp16.h>

// SoftFreezeAttention on MI355X (gfx950).
// out = softmax_rows(exp(-cdist(X,P)/efft)) @ V  with NO max-subtraction
// (reference underflows to 0; computed honestly).
//
// All-fp8 two-pass pipeline (chunks=1):
//   prep_all: X->X8+x2, P->P8+p2, V->Vt8 (fp8,transposed), invt  (1 launch)
//   passA: fp8 GEMM X8.P8^T -> W8 = exp(-dist*invt) via f16 LDS tile,
//          coalesced nt int4 stores + readback rowsum partials. N-loop x4.
//   rowsum_k; passB: fp8 GEMM O^T = Vt8 . W8^T, transpose + normalize.
//
// History: R11 all-fp8 159.3 -> R14 prep-fusion + N-loop = 154.4 (BEST;
// passA 94, VGPR 116, occ 20%) -> R15 T14+full-unroll REGRESS (189.7,
// VGPR 156) -> R16 T14-only REGRESS (199.7, VGPR 144): any added pipeline
// state crosses the 128-VGPR occupancy step, halving blocks/CU; the lost
// wave-level overlap (m114) costs more than the hidden prologue stalls.
// R17 = R14 verbatim + __launch_bounds__(256,2) occupancy guard (VGPR cap
// 128; R14 used 116 -> codegen-neutral, protective only).

typedef _Float16 f16;
typedef _Float16 f16x8 __attribute__((ext_vector_type(8)));
typedef float f32x4 __attribute__((ext_vector_type(4)));
typedef int i32x4 __attribute__((ext_vector_type(4)));
typedef unsigned char u8;

#define DEV __device__ __forceinline__

DEV void gload16(const void* g, void* l) {
  __builtin_amdgcn_global_load_lds(
      (const __attribute__((address_space(1))) void*)g,
      (__attribute__((address_space(3))) void*)l, 16, 0, 0);
}

// pack 4 f32 -> 4 fp8 e4m3 bytes (OCP), little-endian [a,b,c,d]
DEV int pack4_fp8(float a, float b, float c, float d) {
  int lo = __builtin_amdgcn_cvt_pk_fp8_f32(a, b, 0, false);
  int hi = __builtin_amdgcn_cvt_pk_fp8_f32(c, d, 0, false);
  return (hi << 16) | (lo & 0xffff);
}

// ---------------------------------------------------------------- fused prep

DEV void row_pack(const float* __restrict__ src, u8* __restrict__ dst,
                  float* __restrict__ sq, int blk) {
  int row  = blk * 4 + (threadIdx.x >> 6);
  int lane = threadIdx.x & 63;
  const float* r = src + (size_t)row * 512 + lane * 8;
  float4 a = *(const float4*)r;
  float4 b = *(const float4*)(r + 4);
  int2 pk;
  pk.x = pack4_fp8(a.x, a.y, a.z, a.w);
  pk.y = pack4_fp8(b.x, b.y, b.z, b.w);
  *(int2*)(dst + (size_t)row * 512 + lane * 8) = pk;
  float ss = a.x*a.x + a.y*a.y + a.z*a.z + a.w*a.w
           + b.x*b.x + b.y*b.y + b.z*b.z + b.w*b.w;
  ss += __shfl_xor(ss, 1);  ss += __shfl_xor(ss, 2);  ss += __shfl_xor(ss, 4);
  ss += __shfl_xor(ss, 8);  ss += __shfl_xor(ss, 16); ss += __shfl_xor(ss, 32);
  if (lane == 0) sq[row] = ss;
}

__global__ __launch_bounds__(256) void prep_all(
    const float* __restrict__ x, const float* __restrict__ pos,
    const float* __restrict__ val, const float* __restrict__ T,
    const float* __restrict__ ns,
    u8* __restrict__ X8, u8* __restrict__ P8, u8* __restrict__ Vt8,
    float* __restrict__ x2, float* __restrict__ p2,
    float* __restrict__ invt) {
  __shared__ f16 Tt[64][72];
  int b = blockIdx.x;
  if (b < 4096) {                      // X: 16384 rows
    row_pack(x, X8, x2, b);
  } else if (b < 5120) {               // P: 4096 rows
    row_pack(pos, P8, p2, b - 4096);
  } else if (b < 5632) {               // Vt: 512 64x64 tiles
    int id = b - 5120;
    int n0 = (id & 63) * 64, d0 = (id >> 6) * 64;
    int t = threadIdx.x;
#pragma unroll
    for (int rr = 0; rr < 4; ++rr) {
      int r  = (t >> 4) + rr * 16;
      int cq = t & 15;
      float4 v = *(const float4*)(val + (size_t)(n0 + r) * 512 + d0 + cq * 4);
      Tt[cq*4+0][r] = (f16)v.x; Tt[cq*4+1][r] = (f16)v.y;
      Tt[cq*4+2][r] = (f16)v.z; Tt[cq*4+3][r] = (f16)v.w;
    }
    __syncthreads();
    int rd = t >> 2, part = t & 3;
    f16x8 o0 = *(const f16x8*)&Tt[rd][part * 16];
    f16x8 o1 = *(const f16x8*)&Tt[rd][part * 16 + 8];
    i32x4 pk;
    pk.x = pack4_fp8((float)o0[0], (float)o0[1], (float)o0[2], (float)o0[3]);
    pk.y = pack4_fp8((float)o0[4], (float)o0[5], (float)o0[6], (float)o0[7]);
    pk.z = pack4_fp8((float)o1[0], (float)o1[1], (float)o1[2], (float)o1[3]);
    pk.w = pack4_fp8((float)o1[4], (float)o1[5], (float)o1[6], (float)o1[7]);
    *(i32x4*)(Vt8 + (size_t)(d0 + rd) * 4096 + n0 + part * 16) = pk;
  } else {                             // invt: 16 blocks x 256
    int i = (b - 5632) * 256 + threadIdx.x;
    invt[i] = 1.0f / ((fabsf(T[i]) + 0.1f) * ns[i]);
  }
}

// ------------------------------------------------- main GEMM (C = A . B^T form)
// All-fp8. 128x128 tile, 4 waves 2x2, 4x4 16x16x32 frags/wave.
// K-tile = 128 B = 128 fp8. LDS dbuf [As0|Bs0|As1|Bs1] = 64KB. Tiles
// [128 r][128 B]; 16B-chunk o of row r stored at o^(r&7); global_load_lds
// with pre-swizzled per-lane source. 2-phase: stage(next) BEFORE
// compute(cur), one barrier/iter. EPI 0: N-loop nrep=4.
// __launch_bounds__(256,2): hard 2-blocks/CU floor (VGPR cap 128) — R15/R16
// showed any state crossing 128 halves occupancy and regresses.
template <int EPI>
__global__ __launch_bounds__(256, 2) void gemm_bt(
    const void* __restrict__ A, const void* __restrict__ B, int Kb, int gx,
    const float* __restrict__ x2, const float* __restrict__ p2,
    const float* __restrict__ invt, u8* __restrict__ Wout,
    float* __restrict__ Wpart,
    const float* __restrict__ rowsum, float* __restrict__ outp) {
  __shared__ __align__(16) char smem[65536];
  char* As = smem;            // +cur: 0 or 32768
  char* Bs = smem + 16384;

  const int nwg = gridDim.x;
  const int sid = (blockIdx.x & 7) * (nwg >> 3) + (blockIdx.x >> 3);
  const int bx = sid % gx, by = sid / gx;

  const int tid = threadIdx.x, lane = tid & 63, w = tid >> 6;
  const int wrow = (w >> 1) * 64, wcol = (w & 1) * 64;
  const int g = lane >> 4, r15 = lane & 15;
  const int m0 = by * 128;

  const char* Ablk = (const char*)A + (size_t)m0 * Kb;

  const int lr = lane >> 3;
  const int lo = (lane & 7) ^ lr;
  const char* aSrc[4]; char* aDst[4]; char* bDst[4];
  int srow[4];
#pragma unroll
  for (int i = 0; i < 4; ++i) {
    int cb  = w * 4 + i;
    srow[i] = cb * 8 + lr;
    aSrc[i] = Ablk + (size_t)srow[i] * Kb + 16 * lo;
    aDst[i] = As + cb * 1024;
    bDst[i] = Bs + cb * 1024;
  }

  int abase[4], asw[4], bbase[4], bsw[4];
#pragma unroll
  for (int mt = 0; mt < 4; ++mt) {
    int r = wrow + mt * 16 + r15;
    abase[mt] = r * 128; asw[mt] = (r & 7) << 4;
    int rb = wcol + mt * 16 + r15;
    bbase[mt] = rb * 128; bsw[mt] = (rb & 7) << 4;
  }

  const int NIT = Kb >> 7;
  constexpr int nrep = (EPI == 0) ? 4 : 1;

  for (int j = 0; j < nrep; ++j) {
    const int bxj = bx * nrep + j;
    const int n0 = bxj * 128;
    const char* Bblk = (const char*)B + (size_t)n0 * Kb;
    const char* bSrc[4];
#pragma unroll
    for (int i = 0; i < 4; ++i)
      bSrc[i] = Bblk + (size_t)srow[i] * Kb + 16 * lo;

    __syncthreads();              // smem safe to reuse (Wt readers done)
    f32x4 acc[4][4] = {};
#pragma unroll
    for (int i = 0; i < 4; ++i) gload16(aSrc[i], aDst[i]);
#pragma unroll
    for (int i = 0; i < 4; ++i) gload16(bSrc[i], bDst[i]);
    __syncthreads();

#pragma unroll 2
    for (int it = 0; it < NIT; ++it) {
      const int cur = (it & 1) << 15;
      const int nxt = cur ^ 32768;
      if (it + 1 < NIT) {                  // issue next-tile loads FIRST
        const int kb1 = (it + 1) << 7;
#pragma unroll
        for (int i = 0; i < 4; ++i) gload16(aSrc[i] + kb1, aDst[i] + nxt);
#pragma unroll
        for (int i = 0; i < 4; ++i) gload16(bSrc[i] + kb1, bDst[i] + nxt);
      }
      const char* As_ = As + cur;
      const char* Bs_ = Bs + cur;
#pragma unroll
      for (int ks = 0; ks < 4; ++ks) {     // 4 k-slices of K=32 fp8
        long aL[4], bL[4];
#pragma unroll
        for (int mt = 0; mt < 4; ++mt)
          aL[mt] = *(const long*)(As_ + (abase[mt] + ((32 * ks + 8 * g) ^ asw[mt])));
#pragma unroll
        for (int nt = 0; nt < 4; ++nt)
          bL[nt] = *(const long*)(Bs_ + (bbase[nt] + ((32 * ks + 8 * g) ^ bsw[nt])));
#pragma unroll
        for (int mt = 0; mt < 4; ++mt)
#pragma unroll
          for (int nt = 0; nt < 4; ++nt)
            acc[mt][nt] = __builtin_amdgcn_mfma_f32_16x16x32_fp8_fp8(aL[mt], bL[nt],
                                                                     acc[mt][nt], 0, 0, 0);
      }
      __syncthreads();
    }

    if constexpr (EPI == 0) {
      // ---- pass A epilogue: wv = exp(-dist*invt) into f16 LDS tile
      // Wt[128][136] (pad 8, conflict-free readback), then per thread
      // 64 f16 -> sum (rowsum partial) + 4x i32x4 fp8 NT-stores.
      f16* Wt = (f16*)smem;            // overlays dbuf (post-barrier safe)
      int nloc[4]; float p2v[4], itv[4];
#pragma unroll
      for (int nt = 0; nt < 4; ++nt) {
        int nl = wcol + nt * 16 + r15;
        nloc[nt] = nl; p2v[nt] = p2[n0 + nl]; itv[nt] = invt[n0 + nl];
      }
#pragma unroll
      for (int mt = 0; mt < 4; ++mt) {
#pragma unroll
        for (int reg = 0; reg < 4; ++reg) {
          int ml = wrow + mt * 16 + g * 4 + reg;
          float xx = x2[m0 + ml];
#pragma unroll
          for (int nt = 0; nt < 4; ++nt) {
            float d2 = xx + p2v[nt] - 2.0f * acc[mt][nt][reg];
            float dist = __builtin_amdgcn_sqrtf(fmaxf(d2, 0.0f));
            float wv = __expf(-dist * itv[nt]);
            Wt[ml * 136 + nloc[nt]] = (f16)wv;
          }
        }
      }
      __syncthreads();
      {
        int r = tid >> 1, half = tid & 1;
        const f16* srcp = Wt + r * 136 + half * 64;
        float s = 0.f;
        int wds[16];
#pragma unroll
        for (int i = 0; i < 8; ++i) {
          f16x8 v = *(const f16x8*)(srcp + i * 8);
          float f0=(float)v[0], f1=(float)v[1], f2=(float)v[2], f3=(float)v[3];
          float f4=(float)v[4], f5=(float)v[5], f6=(float)v[6], f7=(float)v[7];
          s += f0+f1+f2+f3+f4+f5+f6+f7;
          wds[i*2]   = pack4_fp8(f0, f1, f2, f3);
          wds[i*2+1] = pack4_fp8(f4, f5, f6, f7);
        }
        u8* dstp = Wout + (size_t)(m0 + r) * 4096 + n0 + half * 64;
#pragma unroll
        for (int q = 0; q < 4; ++q) {
          i32x4 st = { wds[q*4], wds[q*4+1], wds[q*4+2], wds[q*4+3] };
          __builtin_nontemporal_store(st, (i32x4*)(dstp + q * 16));
        }
        Wpart[(size_t)(m0 + r) * 64 + bxj * 2 + half] = s;
      }
    } else {
      // ---- pass B epilogue: O^T transpose via per-wave LDS + normalize
      float* Tb = (float*)(smem) + w * (32 * 66);
      const int dl = lane & 31, half = lane >> 5;
#pragma unroll
      for (int h = 0; h < 2; ++h) {
#pragma unroll
        for (int mh = 0; mh < 2; ++mh) {
          int mt = h * 2 + mh;
#pragma unroll
          for (int nt = 0; nt < 4; ++nt)
#pragma unroll
            for (int reg = 0; reg < 4; ++reg)
              Tb[(mh * 16 + g * 4 + reg) * 66 + nt * 16 + r15] = acc[mt][nt][reg];
        }
#pragma unroll
        for (int rr = 0; rr < 32; ++rr) {
          int mloc = rr * 2 + half;
          float v = Tb[dl * 66 + mloc];
          int mg = n0 + wcol + mloc;
          int dg = m0 + wrow + h * 32 + dl;
          float nrm = 1.0f / (rowsum[mg] + 1e-8f);
          __builtin_nontemporal_store(v * nrm, &outp[(size_t)mg * 512 + dg]);
        }
        __syncthreads();  // Tb reused next h
      }
    }
  }
}

// rowsum[m] = sum of 64 partials
__global__ __launch_bounds__(256) void rowsum_k(const float* __restrict__ Wpart,
                                                float* __restrict__ rowsum) {
  int row  = blockIdx.x * 4 + (threadIdx.x >> 6);
  int lane = threadIdx.x & 63;
  float v = Wpart[(size_t)row * 64 + lane];
  v += __shfl_xor(v, 1);  v += __shfl_xor(v, 2);  v += __shfl_xor(v, 4);
  v += __shfl_xor(v, 8);  v += __shfl_xor(v, 16); v += __shfl_xor(v, 32);
  if (lane == 0) rowsum[row] = v;
}

// ---------------------------------------------------------------------- launch

extern "C" void kernel_launch(void* const* d_in, const int* in_sizes, int n_in,
                              void* d_out, int out_size, void* d_ws, size_t ws_size,
                              hipStream_t stream) {
  const float* x   = (const float*)d_in[0];
  const float* pos = (const float*)d_in[1];
  const float* val = (const float*)d_in[2];
  const float* tmp = (const float*)d_in[3];
  const float* nsc = (const float*)d_in[4];
  float* out = (float*)d_out;

  char* p = (char*)d_ws;
  u8*    X8     = (u8*)p;    p += (size_t)16384 * 512;
  u8*    P8     = (u8*)p;    p += (size_t)4096 * 512;
  u8*    Vt8    = (u8*)p;    p += (size_t)512 * 4096;
  float* x2     = (float*)p; p += (size_t)16384 * 4;
  float* p2     = (float*)p; p += (size_t)4096 * 4;
  float* invt   = (float*)p; p += (size_t)4096 * 4;
  float* rowsum = (float*)p; p += (size_t)16384 * 4;
  float* Wpart  = (float*)p; p += (size_t)16384 * 64 * 4;
  u8*    W8     = (u8*)p;
  size_t fixed  = (size_t)(p - (char*)d_ws);
  size_t wfull  = (size_t)16384 * 4096;   // fp8 W

  if (fixed + wfull > ws_size) return;

  prep_all<<<5648, 256, 0, stream>>>(x, pos, val, tmp, nsc,
                                     X8, P8, Vt8, x2, p2, invt);

  // pass A: Kb = 512 fp8 bytes/row, NIT = 4, N-loop x4 -> grid 8 * 128
  gemm_bt<0><<<8 * 128, 256, 0, stream>>>(
      X8, P8, 512, 8, x2, p2, invt, W8, Wpart, nullptr, nullptr);
  rowsum_k<<<4096, 256, 0, stream>>>(Wpart, rowsum);
  // pass B: Kb = 4096 fp8 bytes/row, NIT = 32
  gemm_bt<1><<<128 * 4, 256, 0, stream>>>(
      Vt8, W8, 4096, 128, nullptr, nullptr, nullptr, nullptr, nullptr,
      rowsum, out);
}

// Round 18
// 153.902 us; speedup vs baseline: 1.2974x; 1.0012x over previous
//
#include <hip/hip_runtime.h>
#include <hip/hip_fp16.h>

// SoftFreezeAttention on MI355X (gfx950).
// out = softmax_rows(exp(-cdist(X,P)/efft)) @ V  with NO max-subtraction
// (reference underflows to 0; computed honestly).
//
// All-fp8 two-pass pipeline (chunks=1):
//   prep_all: X->X8+x2, P->P8+p2, V->Vt8 (fp8,transposed), invt  (1 launch)
//   passA: fp8 GEMM X8.P8^T -> W8 = exp(-dist*invt), N-loop x4, T14
//          epilogue-prefetch, Wt in buf1 (row-XOR chunk swizzle), nt stores.
//   rowsum_k; passB: fp8 GEMM O^T = Vt8 . W8^T, transpose + normalize.
//
// History: R11 159.3 -> R14 154.4 -> R15/R16 T14 grafts REGRESSED because
// the unguarded allocator spent 144-156 VGPR, crossing the 128 step and
// halving blocks/CU. R17 added __launch_bounds__(256,2): VGPR 116->92 (!)
// at the same 154.08 -> 36 VGPRs of headroom under the cliff.
// R18 = R17 + T14 epilogue-prefetch, now WITH the guard: prefetch j+1's
// tile0 into buf0 after the final K-barrier; the epilogue (~1400cy VALU,
// Wt in buf1, row-XOR swizzle <=2-way=free) covers the ~900cy latency;
// the j-top barrier then finds the loads complete. Guard keeps 2 blk/CU.

typedef _Float16 f16;
typedef _Float16 f16x8 __attribute__((ext_vector_type(8)));
typedef float f32x4 __attribute__((ext_vector_type(4)));
typedef int i32x4 __attribute__((ext_vector_type(4)));
typedef unsigned char u8;

#define DEV __device__ __forceinline__

DEV void gload16(const void* g, void* l) {
  __builtin_amdgcn_global_load_lds(
      (const __attribute__((address_space(1))) void*)g,
      (__attribute__((address_space(3))) void*)l, 16, 0, 0);
}

// pack 4 f32 -> 4 fp8 e4m3 bytes (OCP), little-endian [a,b,c,d]
DEV int pack4_fp8(float a, float b, float c, float d) {
  int lo = __builtin_amdgcn_cvt_pk_fp8_f32(a, b, 0, false);
  int hi = __builtin_amdgcn_cvt_pk_fp8_f32(c, d, 0, false);
  return (hi << 16) | (lo & 0xffff);
}

// ---------------------------------------------------------------- fused prep

DEV void row_pack(const float* __restrict__ src, u8* __restrict__ dst,
                  float* __restrict__ sq, int blk) {
  int row  = blk * 4 + (threadIdx.x >> 6);
  int lane = threadIdx.x & 63;
  const float* r = src + (size_t)row * 512 + lane * 8;
  float4 a = *(const float4*)r;
  float4 b = *(const float4*)(r + 4);
  int2 pk;
  pk.x = pack4_fp8(a.x, a.y, a.z, a.w);
  pk.y = pack4_fp8(b.x, b.y, b.z, b.w);
  *(int2*)(dst + (size_t)row * 512 + lane * 8) = pk;
  float ss = a.x*a.x + a.y*a.y + a.z*a.z + a.w*a.w
           + b.x*b.x + b.y*b.y + b.z*b.z + b.w*b.w;
  ss += __shfl_xor(ss, 1);  ss += __shfl_xor(ss, 2);  ss += __shfl_xor(ss, 4);
  ss += __shfl_xor(ss, 8);  ss += __shfl_xor(ss, 16); ss += __shfl_xor(ss, 32);
  if (lane == 0) sq[row] = ss;
}

__global__ __launch_bounds__(256) void prep_all(
    const float* __restrict__ x, const float* __restrict__ pos,
    const float* __restrict__ val, const float* __restrict__ T,
    const float* __restrict__ ns,
    u8* __restrict__ X8, u8* __restrict__ P8, u8* __restrict__ Vt8,
    float* __restrict__ x2, float* __restrict__ p2,
    float* __restrict__ invt) {
  __shared__ f16 Tt[64][72];
  int b = blockIdx.x;
  if (b < 4096) {                      // X: 16384 rows
    row_pack(x, X8, x2, b);
  } else if (b < 5120) {               // P: 4096 rows
    row_pack(pos, P8, p2, b - 4096);
  } else if (b < 5632) {               // Vt: 512 64x64 tiles
    int id = b - 5120;
    int n0 = (id & 63) * 64, d0 = (id >> 6) * 64;
    int t = threadIdx.x;
#pragma unroll
    for (int rr = 0; rr < 4; ++rr) {
      int r  = (t >> 4) + rr * 16;
      int cq = t & 15;
      float4 v = *(const float4*)(val + (size_t)(n0 + r) * 512 + d0 + cq * 4);
      Tt[cq*4+0][r] = (f16)v.x; Tt[cq*4+1][r] = (f16)v.y;
      Tt[cq*4+2][r] = (f16)v.z; Tt[cq*4+3][r] = (f16)v.w;
    }
    __syncthreads();
    int rd = t >> 2, part = t & 3;
    f16x8 o0 = *(const f16x8*)&Tt[rd][part * 16];
    f16x8 o1 = *(const f16x8*)&Tt[rd][part * 16 + 8];
    i32x4 pk;
    pk.x = pack4_fp8((float)o0[0], (float)o0[1], (float)o0[2], (float)o0[3]);
    pk.y = pack4_fp8((float)o0[4], (float)o0[5], (float)o0[6], (float)o0[7]);
    pk.z = pack4_fp8((float)o1[0], (float)o1[1], (float)o1[2], (float)o1[3]);
    pk.w = pack4_fp8((float)o1[4], (float)o1[5], (float)o1[6], (float)o1[7]);
    *(i32x4*)(Vt8 + (size_t)(d0 + rd) * 4096 + n0 + part * 16) = pk;
  } else {                             // invt: 16 blocks x 256
    int i = (b - 5632) * 256 + threadIdx.x;
    invt[i] = 1.0f / ((fabsf(T[i]) + 0.1f) * ns[i]);
  }
}

// ------------------------------------------------- main GEMM (C = A . B^T form)
// All-fp8. 128x128 tile, 4 waves 2x2, 4x4 16x16x32 frags/wave.
// K-tile = 128 B. LDS dbuf [buf0|buf1] = 64KB. Tiles [128 r][128 B];
// 16B-chunk o of row r stored at o^(r&7); global_load_lds pre-swizzled src.
// 2-phase: stage(next) BEFORE compute(cur), one barrier/iter (unroll 2).
// EPI 0: N-loop nrep=4; T14: j+1's tile0 prefetched into buf0 before j's
//        epilogue (Wt lives entirely in buf1, row-XOR chunk swizzle).
// __launch_bounds__(256,2): hard 2-blocks/CU floor (VGPR cap 128); without
// it the allocator spends 144+ VGPR and halves occupancy (R15/R16).
template <int EPI>
__global__ __launch_bounds__(256, 2) void gemm_bt(
    const void* __restrict__ A, const void* __restrict__ B, int Kb, int gx,
    const float* __restrict__ x2, const float* __restrict__ p2,
    const float* __restrict__ invt, u8* __restrict__ Wout,
    float* __restrict__ Wpart,
    const float* __restrict__ rowsum, float* __restrict__ outp) {
  __shared__ __align__(16) char smem[65536];
  char* As = smem;            // +cur: 0 or 32768
  char* Bs = smem + 16384;

  const int nwg = gridDim.x;
  const int sid = (blockIdx.x & 7) * (nwg >> 3) + (blockIdx.x >> 3);
  const int bx = sid % gx, by = sid / gx;

  const int tid = threadIdx.x, lane = tid & 63, w = tid >> 6;
  const int wrow = (w >> 1) * 64, wcol = (w & 1) * 64;
  const int g = lane >> 4, r15 = lane & 15;
  const int m0 = by * 128;

  const char* Ablk = (const char*)A + (size_t)m0 * Kb;

  const int lr = lane >> 3;
  const int lo = (lane & 7) ^ lr;
  const char* aSrc[4]; char* aDst[4]; char* bDst[4];
  int srow[4];
#pragma unroll
  for (int i = 0; i < 4; ++i) {
    int cb  = w * 4 + i;
    srow[i] = cb * 8 + lr;
    aSrc[i] = Ablk + (size_t)srow[i] * Kb + 16 * lo;
    aDst[i] = As + cb * 1024;
    bDst[i] = Bs + cb * 1024;
  }

  int abase[4], asw[4], bbase[4], bsw[4];
#pragma unroll
  for (int mt = 0; mt < 4; ++mt) {
    int r = wrow + mt * 16 + r15;
    abase[mt] = r * 128; asw[mt] = (r & 7) << 4;
    int rb = wcol + mt * 16 + r15;
    bbase[mt] = rb * 128; bsw[mt] = (rb & 7) << 4;
  }

  const int NIT = Kb >> 7;
  constexpr int nrep = (EPI == 0) ? 4 : 1;

  // prologue: stage tile0 of j=0 into buf0
  {
    const char* Bblk0 = (const char*)B + (size_t)(bx * nrep * 128) * Kb;
#pragma unroll
    for (int i = 0; i < 4; ++i) gload16(aSrc[i], aDst[i]);
#pragma unroll
    for (int i = 0; i < 4; ++i)
      gload16(Bblk0 + (size_t)srow[i] * Kb + 16 * lo, bDst[i]);
  }

  for (int j = 0; j < nrep; ++j) {
    const int bxj = bx * nrep + j;
    const int n0 = bxj * 128;
    const char* Bblk = (const char*)B + (size_t)n0 * Kb;
    const char* bSrc[4];
#pragma unroll
    for (int i = 0; i < 4; ++i)
      bSrc[i] = Bblk + (size_t)srow[i] * Kb + 16 * lo;

    // drains tile0 gloads (prologue or previous epilogue's T14 prefetch);
    // retires previous epilogue's Wt(buf1) reads before it=0 stages buf1.
    __syncthreads();
    f32x4 acc[4][4] = {};

#pragma unroll 2
    for (int it = 0; it < NIT; ++it) {
      const int cur = (it & 1) << 15;
      const int nxt = cur ^ 32768;
      if (it + 1 < NIT) {                  // issue next-tile loads FIRST
        const int kb1 = (it + 1) << 7;
#pragma unroll
        for (int i = 0; i < 4; ++i) gload16(aSrc[i] + kb1, aDst[i] + nxt);
#pragma unroll
        for (int i = 0; i < 4; ++i) gload16(bSrc[i] + kb1, bDst[i] + nxt);
      }
      const char* As_ = As + cur;
      const char* Bs_ = Bs + cur;
#pragma unroll
      for (int ks = 0; ks < 4; ++ks) {     // 4 k-slices of K=32 fp8
        long aL[4], bL[4];
#pragma unroll
        for (int mt = 0; mt < 4; ++mt)
          aL[mt] = *(const long*)(As_ + (abase[mt] + ((32 * ks + 8 * g) ^ asw[mt])));
#pragma unroll
        for (int nt = 0; nt < 4; ++nt)
          bL[nt] = *(const long*)(Bs_ + (bbase[nt] + ((32 * ks + 8 * g) ^ bsw[nt])));
#pragma unroll
        for (int mt = 0; mt < 4; ++mt)
#pragma unroll
          for (int nt = 0; nt < 4; ++nt)
            acc[mt][nt] = __builtin_amdgcn_mfma_f32_16x16x32_fp8_fp8(aL[mt], bL[nt],
                                                                     acc[mt][nt], 0, 0, 0);
      }
      __syncthreads();
    }
    // after the final barrier all buffer reads are retired.

    if constexpr (EPI == 0) {
      // T14 prefetch: issue j+1's tile0 into buf0 NOW; the epilogue below
      // covers its latency. Wt lives entirely in buf1 so no overlap.
      if (j + 1 < nrep) {
        const char* Bn = (const char*)B + (size_t)((bxj + 1) * 128) * Kb;
#pragma unroll
        for (int i = 0; i < 4; ++i) gload16(aSrc[i], aDst[i]);
#pragma unroll
        for (int i = 0; i < 4; ++i)
          gload16(Bn + (size_t)srow[i] * Kb + 16 * lo, bDst[i]);
      }
      // ---- epilogue: wv = exp(-dist*invt) -> Wt (buf1, [128 rows][256B]
      // f16, row-XOR chunk swizzle: byte = ml*256 + ((2*nl) ^ ((ml&7)<<4)))
      // -> coalesced readback: sum + fp8 pack + 4x i32x4 nt-stores.
      char* Wt = smem + 32768;
      int nloc[4]; float p2v[4], itv[4];
#pragma unroll
      for (int nt = 0; nt < 4; ++nt) {
        int nl = wcol + nt * 16 + r15;
        nloc[nt] = nl; p2v[nt] = p2[n0 + nl]; itv[nt] = invt[n0 + nl];
      }
#pragma unroll
      for (int mt = 0; mt < 4; ++mt) {
#pragma unroll
        for (int reg = 0; reg < 4; ++reg) {
          int ml = wrow + mt * 16 + g * 4 + reg;
          int mlsw = (ml & 7) << 4;
          float xx = x2[m0 + ml];
#pragma unroll
          for (int nt = 0; nt < 4; ++nt) {
            float d2 = xx + p2v[nt] - 2.0f * acc[mt][nt][reg];
            float dist = __builtin_amdgcn_sqrtf(fmaxf(d2, 0.0f));
            float wv = __expf(-dist * itv[nt]);
            *(f16*)(Wt + ml * 256 + ((2 * nloc[nt]) ^ mlsw)) = (f16)wv;
          }
        }
      }
      __syncthreads();
      {
        int r = tid >> 1, half = tid & 1;
        int r7 = r & 7;
        float s = 0.f;
        int wds[16];
#pragma unroll
        for (int i = 0; i < 8; ++i) {
          int c = half * 8 + i;                 // logical 16B chunk
          f16x8 v = *(const f16x8*)(Wt + r * 256 + ((c ^ r7) << 4));
          float f0=(float)v[0], f1=(float)v[1], f2=(float)v[2], f3=(float)v[3];
          float f4=(float)v[4], f5=(float)v[5], f6=(float)v[6], f7=(float)v[7];
          s += f0+f1+f2+f3+f4+f5+f6+f7;
          wds[i*2]   = pack4_fp8(f0, f1, f2, f3);
          wds[i*2+1] = pack4_fp8(f4, f5, f6, f7);
        }
        u8* dstp = Wout + (size_t)(m0 + r) * 4096 + n0 + half * 64;
#pragma unroll
        for (int q = 0; q < 4; ++q) {
          i32x4 st = { wds[q*4], wds[q*4+1], wds[q*4+2], wds[q*4+3] };
          __builtin_nontemporal_store(st, (i32x4*)(dstp + q * 16));
        }
        Wpart[(size_t)(m0 + r) * 64 + bxj * 2 + half] = s;
      }
    } else {
      // ---- pass B epilogue: O^T transpose via per-wave LDS + normalize
      float* Tb = (float*)(smem) + w * (32 * 66);
      const int dl = lane & 31, half = lane >> 5;
#pragma unroll
      for (int h = 0; h < 2; ++h) {
#pragma unroll
        for (int mh = 0; mh < 2; ++mh) {
          int mt = h * 2 + mh;
#pragma unroll
          for (int nt = 0; nt < 4; ++nt)
#pragma unroll
            for (int reg = 0; reg < 4; ++reg)
              Tb[(mh * 16 + g * 4 + reg) * 66 + nt * 16 + r15] = acc[mt][nt][reg];
        }
#pragma unroll
        for (int rr = 0; rr < 32; ++rr) {
          int mloc = rr * 2 + half;
          float v = Tb[dl * 66 + mloc];
          int mg = n0 + wcol + mloc;
          int dg = m0 + wrow + h * 32 + dl;
          float nrm = 1.0f / (rowsum[mg] + 1e-8f);
          __builtin_nontemporal_store(v * nrm, &outp[(size_t)mg * 512 + dg]);
        }
        __syncthreads();  // Tb reused next h
      }
    }
  }
}

// rowsum[m] = sum of 64 partials
__global__ __launch_bounds__(256) void rowsum_k(const float* __restrict__ Wpart,
                                                float* __restrict__ rowsum) {
  int row  = blockIdx.x * 4 + (threadIdx.x >> 6);
  int lane = threadIdx.x & 63;
  float v = Wpart[(size_t)row * 64 + lane];
  v += __shfl_xor(v, 1);  v += __shfl_xor(v, 2);  v += __shfl_xor(v, 4);
  v += __shfl_xor(v, 8);  v += __shfl_xor(v, 16); v += __shfl_xor(v, 32);
  if (lane == 0) rowsum[row] = v;
}

// ---------------------------------------------------------------------- launch

extern "C" void kernel_launch(void* const* d_in, const int* in_sizes, int n_in,
                              void* d_out, int out_size, void* d_ws, size_t ws_size,
                              hipStream_t stream) {
  const float* x   = (const float*)d_in[0];
  const float* pos = (const float*)d_in[1];
  const float* val = (const float*)d_in[2];
  const float* tmp = (const float*)d_in[3];
  const float* nsc = (const float*)d_in[4];
  float* out = (float*)d_out;

  char* p = (char*)d_ws;
  u8*    X8     = (u8*)p;    p += (size_t)16384 * 512;
  u8*    P8     = (u8*)p;    p += (size_t)4096 * 512;
  u8*    Vt8    = (u8*)p;    p += (size_t)512 * 4096;
  float* x2     = (float*)p; p += (size_t)16384 * 4;
  float* p2     = (float*)p; p += (size_t)4096 * 4;
  float* invt   = (float*)p; p += (size_t)4096 * 4;
  float* rowsum = (float*)p; p += (size_t)16384 * 4;
  float* Wpart  = (float*)p; p += (size_t)16384 * 64 * 4;
  u8*    W8     = (u8*)p;
  size_t fixed  = (size_t)(p - (char*)d_ws);
  size_t wfull  = (size_t)16384 * 4096;   // fp8 W

  if (fixed + wfull > ws_size) return;

  prep_all<<<5648, 256, 0, stream>>>(x, pos, val, tmp, nsc,
                                     X8, P8, Vt8, x2, p2, invt);

  // pass A: Kb = 512 fp8 bytes/row, NIT = 4, N-loop x4 -> grid 8 * 128
  gemm_bt<0><<<8 * 128, 256, 0, stream>>>(
      X8, P8, 512, 8, x2, p2, invt, W8, Wpart, nullptr, nullptr);
  rowsum_k<<<4096, 256, 0, stream>>>(Wpart, rowsum);
  // pass B: Kb = 4096 fp8 bytes/row, NIT = 32
  gemm_bt<1><<<128 * 4, 256, 0, stream>>>(
      Vt8, W8, 4096, 128, nullptr, nullptr, nullptr, nullptr, nullptr,
      rowsum, out);
}

// Round 19
// 140.294 us; speedup vs baseline: 1.4232x; 1.0970x over previous
//
#include <hip/hip_runtime.h>
#include <hip/hip_fp16.h>

// SoftFreezeAttention on MI355X (gfx950).
// out = softmax_rows(exp(-cdist(X,P)/efft)) @ V  with NO max-subtraction
// (reference underflows to 0; computed honestly).
//
// All-fp8 two-pass pipeline (chunks=1):
//   prep_all: X->X8+x2, P->P8+p2, V->Vt8 (fp8, transposed, n-PERMUTED), invt
//   passA: fp8 GEMM X8.P8^T -> W8 = exp(-dist*invt), N-loop x4, T14
//          epilogue-prefetch, DIRECT permuted fp8 dword nt-stores (no f16
//          LDS round-trip), rowsum partials via small Ws LDS slab.
//   rowsum_k; passB: fp8 GEMM O^T = Vt8 . W8^T (contraction over permuted n
//          invariant: both operands share the permutation), transpose+norm.
//
// History: R11 159.3 -> R14 154.4 -> R17 +launch_bounds(256,2) 154.08
// (VGPR 116->92) -> R18 +T14 guarded 153.9 (neutral). passA stuck ~93:
// MFMA 28us, VALU 41us -> epilogue is co-dominant.
// R19: epilogue diet. R12's permuted direct store was right; its regression
// was the 64 shfl_xor + divergent stores it added. Now: pack4_fp8 direct
// from f32 (kills 128 f16 cvts), one nt dword store per (mt,reg), rowsum
// via Ws[128][36] f32 slab (16 b32 writes vs 64 b16 + 16 b128 before).

typedef _Float16 f16;
typedef _Float16 f16x8 __attribute__((ext_vector_type(8)));
typedef float f32x4 __attribute__((ext_vector_type(4)));
typedef int i32x4 __attribute__((ext_vector_type(4)));
typedef unsigned char u8;

#define DEV __device__ __forceinline__

DEV void gload16(const void* g, void* l) {
  __builtin_amdgcn_global_load_lds(
      (const __attribute__((address_space(1))) void*)g,
      (__attribute__((address_space(3))) void*)l, 16, 0, 0);
}

// pack 4 f32 -> 4 fp8 e4m3 bytes (OCP), little-endian [a,b,c,d]
DEV int pack4_fp8(float a, float b, float c, float d) {
  int lo = __builtin_amdgcn_cvt_pk_fp8_f32(a, b, 0, false);
  int hi = __builtin_amdgcn_cvt_pk_fp8_f32(c, d, 0, false);
  return (hi << 16) | (lo & 0xffff);
}

// ---------------------------------------------------------------- fused prep

DEV void row_pack(const float* __restrict__ src, u8* __restrict__ dst,
                  float* __restrict__ sq, int blk) {
  int row  = blk * 4 + (threadIdx.x >> 6);
  int lane = threadIdx.x & 63;
  const float* r = src + (size_t)row * 512 + lane * 8;
  float4 a = *(const float4*)r;
  float4 b = *(const float4*)(r + 4);
  int2 pk;
  pk.x = pack4_fp8(a.x, a.y, a.z, a.w);
  pk.y = pack4_fp8(b.x, b.y, b.z, b.w);
  *(int2*)(dst + (size_t)row * 512 + lane * 8) = pk;
  float ss = a.x*a.x + a.y*a.y + a.z*a.z + a.w*a.w
           + b.x*b.x + b.y*b.y + b.z*b.z + b.w*b.w;
  ss += __shfl_xor(ss, 1);  ss += __shfl_xor(ss, 2);  ss += __shfl_xor(ss, 4);
  ss += __shfl_xor(ss, 8);  ss += __shfl_xor(ss, 16); ss += __shfl_xor(ss, 32);
  if (lane == 0) sq[row] = ss;
}

__global__ __launch_bounds__(256) void prep_all(
    const float* __restrict__ x, const float* __restrict__ pos,
    const float* __restrict__ val, const float* __restrict__ T,
    const float* __restrict__ ns,
    u8* __restrict__ X8, u8* __restrict__ P8, u8* __restrict__ Vt8,
    float* __restrict__ x2, float* __restrict__ p2,
    float* __restrict__ invt) {
  __shared__ f16 Tt[64][72];
  int b = blockIdx.x;
  if (b < 4096) {                      // X: 16384 rows
    row_pack(x, X8, x2, b);
  } else if (b < 5120) {               // P: 4096 rows
    row_pack(pos, P8, p2, b - 4096);
  } else if (b < 5632) {               // Vt: 512 64x64 tiles, pi-permuted n:
    // Vt8[d][blk*64 + r*4 + nt] = fp8(V[blk*64 + nt*16 + r][d])
    int id = b - 5120;
    int n0 = (id & 63) * 64, d0 = (id >> 6) * 64;
    int t = threadIdx.x;
#pragma unroll
    for (int rr = 0; rr < 4; ++rr) {
      int r  = (t >> 4) + rr * 16;
      int cq = t & 15;
      float4 v = *(const float4*)(val + (size_t)(n0 + r) * 512 + d0 + cq * 4);
      Tt[cq*4+0][r] = (f16)v.x; Tt[cq*4+1][r] = (f16)v.y;
      Tt[cq*4+2][r] = (f16)v.z; Tt[cq*4+3][r] = (f16)v.w;
    }
    __syncthreads();
    int rd = t >> 2, part = t & 3;   // dest 16B chunk q = part*16 + j
    int p4 = part * 4;
    i32x4 pk;
    // byte j of chunk: src n-local = (j&3)*16 + p4 + (j>>2)
    pk.x = pack4_fp8((float)Tt[rd][p4+0], (float)Tt[rd][16+p4+0],
                     (float)Tt[rd][32+p4+0], (float)Tt[rd][48+p4+0]);
    pk.y = pack4_fp8((float)Tt[rd][p4+1], (float)Tt[rd][16+p4+1],
                     (float)Tt[rd][32+p4+1], (float)Tt[rd][48+p4+1]);
    pk.z = pack4_fp8((float)Tt[rd][p4+2], (float)Tt[rd][16+p4+2],
                     (float)Tt[rd][32+p4+2], (float)Tt[rd][48+p4+2]);
    pk.w = pack4_fp8((float)Tt[rd][p4+3], (float)Tt[rd][16+p4+3],
                     (float)Tt[rd][32+p4+3], (float)Tt[rd][48+p4+3]);
    *(i32x4*)(Vt8 + (size_t)(d0 + rd) * 4096 + n0 + part * 16) = pk;
  } else {                             // invt: 16 blocks x 256
    int i = (b - 5632) * 256 + threadIdx.x;
    invt[i] = 1.0f / ((fabsf(T[i]) + 0.1f) * ns[i]);
  }
}

// ------------------------------------------------- main GEMM (C = A . B^T form)
// All-fp8. 128x128 tile, 4 waves 2x2, 4x4 16x16x32 frags/wave.
// K-tile = 128 B. LDS dbuf [buf0|buf1] = 64KB. Tiles [128 r][128 B];
// 16B-chunk o of row r stored at o^(r&7); global_load_lds pre-swizzled src.
// 2-phase: stage(next) BEFORE compute(cur), one barrier/iter (unroll 2).
// EPI 0: N-loop nrep=4; T14 prefetch of j+1's tile0 into buf0 before j's
//        epilogue; epilogue = direct permuted fp8 stores + Ws rowsum slab
//        (buf1, [128][36] f32: pad 36 keeps 16B-aligned rows, 2-way banks).
// __launch_bounds__(256,2): hard 2-blocks/CU floor (VGPR cap 128).
template <int EPI>
__global__ __launch_bounds__(256, 2) void gemm_bt(
    const void* __restrict__ A, const void* __restrict__ B, int Kb, int gx,
    const float* __restrict__ x2, const float* __restrict__ p2,
    const float* __restrict__ invt, u8* __restrict__ Wout,
    float* __restrict__ Wpart,
    const float* __restrict__ rowsum, float* __restrict__ outp) {
  __shared__ __align__(16) char smem[65536];
  char* As = smem;            // +cur: 0 or 32768
  char* Bs = smem + 16384;

  const int nwg = gridDim.x;
  const int sid = (blockIdx.x & 7) * (nwg >> 3) + (blockIdx.x >> 3);
  const int bx = sid % gx, by = sid / gx;

  const int tid = threadIdx.x, lane = tid & 63, w = tid >> 6;
  const int wrow = (w >> 1) * 64, wcol = (w & 1) * 64;
  const int g = lane >> 4, r15 = lane & 15;
  const int m0 = by * 128;

  const char* Ablk = (const char*)A + (size_t)m0 * Kb;

  const int lr = lane >> 3;
  const int lo = (lane & 7) ^ lr;
  const char* aSrc[4]; char* aDst[4]; char* bDst[4];
  int srow[4];
#pragma unroll
  for (int i = 0; i < 4; ++i) {
    int cb  = w * 4 + i;
    srow[i] = cb * 8 + lr;
    aSrc[i] = Ablk + (size_t)srow[i] * Kb + 16 * lo;
    aDst[i] = As + cb * 1024;
    bDst[i] = Bs + cb * 1024;
  }

  int abase[4], asw[4], bbase[4], bsw[4];
#pragma unroll
  for (int mt = 0; mt < 4; ++mt) {
    int r = wrow + mt * 16 + r15;
    abase[mt] = r * 128; asw[mt] = (r & 7) << 4;
    int rb = wcol + mt * 16 + r15;
    bbase[mt] = rb * 128; bsw[mt] = (rb & 7) << 4;
  }

  const int NIT = Kb >> 7;
  constexpr int nrep = (EPI == 0) ? 4 : 1;

  // prologue: stage tile0 of j=0 into buf0
  {
    const char* Bblk0 = (const char*)B + (size_t)(bx * nrep * 128) * Kb;
#pragma unroll
    for (int i = 0; i < 4; ++i) gload16(aSrc[i], aDst[i]);
#pragma unroll
    for (int i = 0; i < 4; ++i)
      gload16(Bblk0 + (size_t)srow[i] * Kb + 16 * lo, bDst[i]);
  }

  for (int j = 0; j < nrep; ++j) {
    const int bxj = bx * nrep + j;
    const int n0 = bxj * 128;
    const char* Bblk = (const char*)B + (size_t)n0 * Kb;
    const char* bSrc[4];
#pragma unroll
    for (int i = 0; i < 4; ++i)
      bSrc[i] = Bblk + (size_t)srow[i] * Kb + 16 * lo;

    // drains tile0 gloads (prologue or T14 prefetch); retires previous
    // epilogue's Ws(buf1) reads before it=0 stages buf1.
    __syncthreads();
    f32x4 acc[4][4] = {};

#pragma unroll 2
    for (int it = 0; it < NIT; ++it) {
      const int cur = (it & 1) << 15;
      const int nxt = cur ^ 32768;
      if (it + 1 < NIT) {                  // issue next-tile loads FIRST
        const int kb1 = (it + 1) << 7;
#pragma unroll
        for (int i = 0; i < 4; ++i) gload16(aSrc[i] + kb1, aDst[i] + nxt);
#pragma unroll
        for (int i = 0; i < 4; ++i) gload16(bSrc[i] + kb1, bDst[i] + nxt);
      }
      const char* As_ = As + cur;
      const char* Bs_ = Bs + cur;
#pragma unroll
      for (int ks = 0; ks < 4; ++ks) {     // 4 k-slices of K=32 fp8
        long aL[4], bL[4];
#pragma unroll
        for (int mt = 0; mt < 4; ++mt)
          aL[mt] = *(const long*)(As_ + (abase[mt] + ((32 * ks + 8 * g) ^ asw[mt])));
#pragma unroll
        for (int nt = 0; nt < 4; ++nt)
          bL[nt] = *(const long*)(Bs_ + (bbase[nt] + ((32 * ks + 8 * g) ^ bsw[nt])));
#pragma unroll
        for (int mt = 0; mt < 4; ++mt)
#pragma unroll
          for (int nt = 0; nt < 4; ++nt)
            acc[mt][nt] = __builtin_amdgcn_mfma_f32_16x16x32_fp8_fp8(aL[mt], bL[nt],
                                                                     acc[mt][nt], 0, 0, 0);
      }
      __syncthreads();
    }
    // after the final barrier all buffer reads are retired.

    if constexpr (EPI == 0) {
      // T14 prefetch: j+1's tile0 into buf0 NOW; epilogue covers latency.
      if (j + 1 < nrep) {
        const char* Bn = (const char*)B + (size_t)((bxj + 1) * 128) * Kb;
#pragma unroll
        for (int i = 0; i < 4; ++i) gload16(aSrc[i], aDst[i]);
#pragma unroll
        for (int i = 0; i < 4; ++i)
          gload16(Bn + (size_t)srow[i] * Kb + 16 * lo, bDst[i]);
      }
      // ---- epilogue (no f16 round-trip): per (mt,reg): 4x exp -> pack4
      // straight to fp8 -> ONE permuted nt dword store
      // (W col' = wcol + 4*r15 + nt  <->  orig col wcol + nt*16 + r15,
      // matching prep_vt's pi so pass B's contraction is invariant).
      // Row-partials to Ws[128][36] f32 in buf1 (16B-aligned rows).
      float* Ws = (float*)(smem + 32768);
      float p2v[4], itv[4];
#pragma unroll
      for (int nt = 0; nt < 4; ++nt) {
        int n = n0 + wcol + nt * 16 + r15;
        p2v[nt] = p2[n]; itv[nt] = invt[n];
      }
      u8* wbase = Wout + n0 + wcol + 4 * r15;
#pragma unroll
      for (int mt = 0; mt < 4; ++mt) {
#pragma unroll
        for (int reg = 0; reg < 4; ++reg) {
          int ml = wrow + mt * 16 + g * 4 + reg;
          float xx = x2[m0 + ml];
          float wv0, wv1, wv2, wv3;
          {
            float d2 = xx + p2v[0] - 2.0f * acc[mt][0][reg];
            wv0 = __expf(-__builtin_amdgcn_sqrtf(fmaxf(d2, 0.0f)) * itv[0]);
            d2 = xx + p2v[1] - 2.0f * acc[mt][1][reg];
            wv1 = __expf(-__builtin_amdgcn_sqrtf(fmaxf(d2, 0.0f)) * itv[1]);
            d2 = xx + p2v[2] - 2.0f * acc[mt][2][reg];
            wv2 = __expf(-__builtin_amdgcn_sqrtf(fmaxf(d2, 0.0f)) * itv[2]);
            d2 = xx + p2v[3] - 2.0f * acc[mt][3][reg];
            wv3 = __expf(-__builtin_amdgcn_sqrtf(fmaxf(d2, 0.0f)) * itv[3]);
          }
          int dw = pack4_fp8(wv0, wv1, wv2, wv3);
          __builtin_nontemporal_store(dw, (int*)(wbase + (size_t)(m0 + ml) * 4096));
          Ws[ml * 36 + (w & 1) * 16 + r15] = wv0 + wv1 + wv2 + wv3;
        }
      }
      __syncthreads();
      {
        int r = tid >> 1, half = tid & 1;
        const float* sp = Ws + r * 36 + half * 16;
        float4 a0 = *(const float4*)(sp);
        float4 a1 = *(const float4*)(sp + 4);
        float4 a2 = *(const float4*)(sp + 8);
        float4 a3 = *(const float4*)(sp + 12);
        float s = a0.x+a0.y+a0.z+a0.w + a1.x+a1.y+a1.z+a1.w
                + a2.x+a2.y+a2.z+a2.w + a3.x+a3.y+a3.z+a3.w;
        Wpart[(size_t)(m0 + r) * 64 + bxj * 2 + half] = s;
      }
    } else {
      // ---- pass B epilogue: O^T transpose via per-wave LDS + normalize
      float* Tb = (float*)(smem) + w * (32 * 66);
      const int dl = lane & 31, half = lane >> 5;
#pragma unroll
      for (int h = 0; h < 2; ++h) {
#pragma unroll
        for (int mh = 0; mh < 2; ++mh) {
          int mt = h * 2 + mh;
#pragma unroll
          for (int nt = 0; nt < 4; ++nt)
#pragma unroll
            for (int reg = 0; reg < 4; ++reg)
              Tb[(mh * 16 + g * 4 + reg) * 66 + nt * 16 + r15] = acc[mt][nt][reg];
        }
#pragma unroll
        for (int rr = 0; rr < 32; ++rr) {
          int mloc = rr * 2 + half;
          float v = Tb[dl * 66 + mloc];
          int mg = n0 + wcol + mloc;
          int dg = m0 + wrow + h * 32 + dl;
          float nrm = 1.0f / (rowsum[mg] + 1e-8f);
          __builtin_nontemporal_store(v * nrm, &outp[(size_t)mg * 512 + dg]);
        }
        __syncthreads();  // Tb reused next h
      }
    }
  }
}

// rowsum[m] = sum of 64 partials
__global__ __launch_bounds__(256) void rowsum_k(const float* __restrict__ Wpart,
                                                float* __restrict__ rowsum) {
  int row  = blockIdx.x * 4 + (threadIdx.x >> 6);
  int lane = threadIdx.x & 63;
  float v = Wpart[(size_t)row * 64 + lane];
  v += __shfl_xor(v, 1);  v += __shfl_xor(v, 2);  v += __shfl_xor(v, 4);
  v += __shfl_xor(v, 8);  v += __shfl_xor(v, 16); v += __shfl_xor(v, 32);
  if (lane == 0) rowsum[row] = v;
}

// ---------------------------------------------------------------------- launch

extern "C" void kernel_launch(void* const* d_in, const int* in_sizes, int n_in,
                              void* d_out, int out_size, void* d_ws, size_t ws_size,
                              hipStream_t stream) {
  const float* x   = (const float*)d_in[0];
  const float* pos = (const float*)d_in[1];
  const float* val = (const float*)d_in[2];
  const float* tmp = (const float*)d_in[3];
  const float* nsc = (const float*)d_in[4];
  float* out = (float*)d_out;

  char* p = (char*)d_ws;
  u8*    X8     = (u8*)p;    p += (size_t)16384 * 512;
  u8*    P8     = (u8*)p;    p += (size_t)4096 * 512;
  u8*    Vt8    = (u8*)p;    p += (size_t)512 * 4096;
  float* x2     = (float*)p; p += (size_t)16384 * 4;
  float* p2     = (float*)p; p += (size_t)4096 * 4;
  float* invt   = (float*)p; p += (size_t)4096 * 4;
  float* rowsum = (float*)p; p += (size_t)16384 * 4;
  float* Wpart  = (float*)p; p += (size_t)16384 * 64 * 4;
  u8*    W8     = (u8*)p;
  size_t fixed  = (size_t)(p - (char*)d_ws);
  size_t wfull  = (size_t)16384 * 4096;   // fp8 W

  if (fixed + wfull > ws_size) return;

  prep_all<<<5648, 256, 0, stream>>>(x, pos, val, tmp, nsc,
                                     X8, P8, Vt8, x2, p2, invt);

  // pass A: Kb = 512 fp8 bytes/row, NIT = 4, N-loop x4 -> grid 8 * 128
  gemm_bt<0><<<8 * 128, 256, 0, stream>>>(
      X8, P8, 512, 8, x2, p2, invt, W8, Wpart, nullptr, nullptr);
  rowsum_k<<<4096, 256, 0, stream>>>(Wpart, rowsum);
  // pass B: Kb = 4096 fp8 bytes/row, NIT = 32
  gemm_bt<1><<<128 * 4, 256, 0, stream>>>(
      Vt8, W8, 4096, 128, nullptr, nullptr, nullptr, nullptr, nullptr,
      rowsum, out);
}